// Round 1
// baseline (247.267 us; speedup 1.0000x reference)
//
#include <hip/hip_runtime.h>
#include <hip/hip_bf16.h>
#include <math.h>

// Problem constants (B=4, C=192, H=W=128, KS=3, dilations {1,2,3}, 6 heads)
#define Hdim 128
#define Wdim 128
#define HW   16384
#define Cdim 192
#define Bdim 4
#define QKVC 576            // 3*C
#define NTOT (Bdim * HW)    // 65536 total pixels

typedef __attribute__((ext_vector_type(8))) short short8;   // 8 bf16 (4 VGPRs)
typedef __attribute__((ext_vector_type(4))) short short4v;  // 4 bf16 (8 B)
typedef __attribute__((ext_vector_type(4))) float f32x4;

__device__ __forceinline__ void async_ld16(void* lds, const void* g) {
    __builtin_amdgcn_global_load_lds(
        (const __attribute__((address_space(1))) void*)g,
        (__attribute__((address_space(3))) void*)lds, 16, 0, 0);
}
__device__ __forceinline__ float lo16(unsigned u) { return __uint_as_float(u << 16); }
__device__ __forceinline__ float hi16(unsigned u) { return __uint_as_float(u & 0xffff0000u); }

// ---------------------------------------------------------------------------
// Convert both weight matrices to bf16 (147456 elements total).
// ---------------------------------------------------------------------------
__global__ void convert_w(const float* __restrict__ qkv_w,
                          const float* __restrict__ proj_w,
                          __hip_bfloat16* __restrict__ Wq,
                          __hip_bfloat16* __restrict__ Wp) {
    int i = blockIdx.x * 256 + threadIdx.x;
    if (i < QKVC * Cdim) {
        Wq[i] = __float2bfloat16(qkv_w[i]);
    } else {
        int j = i - QKVC * Cdim;
        Wp[j] = __float2bfloat16(proj_w[j]);
    }
}

// ---------------------------------------------------------------------------
// posconv: depthwise 3x3 (zero pad) + bias + residual, f32 NCHW in ->
// bf16 NHWC out [NTOT][192]. Block = 64-pixel half-row x 192 channels.
// ---------------------------------------------------------------------------
__global__ __launch_bounds__(256, 4)
void posconv_nhwc(const float* __restrict__ x,
                  const float* __restrict__ pos_w,
                  const float* __restrict__ pos_b,
                  __hip_bfloat16* __restrict__ Xb) {
    __shared__ __hip_bfloat16 tile[Cdim][68];   // [c][pixel], pad 64->68
    __shared__ float wts[Cdim * 9];
    __shared__ float bs[Cdim];
    int t = threadIdx.x;
    for (int i = t; i < Cdim * 9; i += 256) wts[i] = pos_w[i];
    if (t < Cdim) bs[t] = pos_b[t];
    __syncthreads();

    int p0 = blockIdx.x * 64;
    int b = p0 >> 14;
    int pimg = p0 & (HW - 1);
    int h = pimg >> 7, wbase = pimg & 127;      // 0 or 64
    const float* xim = x + (size_t)b * Cdim * HW;

#pragma unroll
    for (int it = 0; it < 12; ++it) {
        int quad = t & 15;
        int c = it * 16 + (t >> 4);
        int w0 = wbase + quad * 4;
        const float* xc = xim + (size_t)c * HW;
        const float* wt = wts + c * 9;
        float o0, o1, o2, o3;
        {   // center row: residual + bias + kh=1 taps
            const float* xr = xc + h * Wdim;
            float4 f = *(const float4*)(xr + w0);
            float L = (w0 > 0) ? xr[w0 - 1] : 0.f;
            float R = (w0 + 4 < Wdim) ? xr[w0 + 4] : 0.f;
            float b0 = bs[c];
            float w_0 = wt[3], w_1 = wt[4], w_2 = wt[5];
            o0 = f.x + b0 + w_0 * L   + w_1 * f.x + w_2 * f.y;
            o1 = f.y + b0 + w_0 * f.x + w_1 * f.y + w_2 * f.z;
            o2 = f.z + b0 + w_0 * f.y + w_1 * f.z + w_2 * f.w;
            o3 = f.w + b0 + w_0 * f.z + w_1 * f.w + w_2 * R;
        }
        if (h > 0) {   // row h-1, kh=0
            const float* xr = xc + (h - 1) * Wdim;
            float4 f = *(const float4*)(xr + w0);
            float L = (w0 > 0) ? xr[w0 - 1] : 0.f;
            float R = (w0 + 4 < Wdim) ? xr[w0 + 4] : 0.f;
            float w_0 = wt[0], w_1 = wt[1], w_2 = wt[2];
            o0 += w_0 * L   + w_1 * f.x + w_2 * f.y;
            o1 += w_0 * f.x + w_1 * f.y + w_2 * f.z;
            o2 += w_0 * f.y + w_1 * f.z + w_2 * f.w;
            o3 += w_0 * f.z + w_1 * f.w + w_2 * R;
        }
        if (h < Hdim - 1) {   // row h+1, kh=2
            const float* xr = xc + (h + 1) * Wdim;
            float4 f = *(const float4*)(xr + w0);
            float L = (w0 > 0) ? xr[w0 - 1] : 0.f;
            float R = (w0 + 4 < Wdim) ? xr[w0 + 4] : 0.f;
            float w_0 = wt[6], w_1 = wt[7], w_2 = wt[8];
            o0 += w_0 * L   + w_1 * f.x + w_2 * f.y;
            o1 += w_0 * f.x + w_1 * f.y + w_2 * f.z;
            o2 += w_0 * f.y + w_1 * f.z + w_2 * f.w;
            o3 += w_0 * f.z + w_1 * f.w + w_2 * R;
        }
        short4v pk;
        __hip_bfloat16 bv;
        bv = __float2bfloat16(o0); pk[0] = *(short*)&bv;
        bv = __float2bfloat16(o1); pk[1] = *(short*)&bv;
        bv = __float2bfloat16(o2); pk[2] = *(short*)&bv;
        bv = __float2bfloat16(o3); pk[3] = *(short*)&bv;
        *(short4v*)(void*)&tile[c][quad * 4] = pk;   // one ds_write_b64
    }
    __syncthreads();

    // phase 2: 1536 stores of 16B; lane = pixel (conflict-free LDS reads)
#pragma unroll
    for (int it = 0; it < 6; ++it) {
        int pl = t & 63;
        int cgq = it * 4 + (t >> 6);   // 0..23: channel octet
        union { unsigned short u[8]; short8 v; } o;
#pragma unroll
        for (int j = 0; j < 8; ++j)
            o.u[j] = *(const unsigned short*)&tile[cgq * 8 + j][pl];
        *(short8*)(void*)(Xb + (size_t)(p0 + pl) * Cdim + cgq * 8) = o.v;
    }
}

// ---------------------------------------------------------------------------
// MFMA bf16 GEMM: D[m,n] = sum_k W[m,k] * Xt[n,k]    (K = 192)
// Block 64x256 (4 waves of 64x64, 4x4 frags of 16x16x32). BK=32, 6 K-iters.
// 1-D grid, XCD-aware decode: each XCD runs all MT m-tiles of one n-block
// consecutively -> B-tile fetched into its L2 once, reused MT times.
// MODE 0: B = NHWC [NTOT][192]; store bf16 planes [(three*3+i)*2+nh][NTOT][32].
// MODE 1: B = planes [6][NTOT][32] (K-chunk kt == plane kt);
//         store f32 NCHW out[b][m][p], col n = b*HW + p.
// ---------------------------------------------------------------------------
template <int MODE, int MT>
__global__ __launch_bounds__(256, 2)
void gemm_mfma(const __hip_bfloat16* __restrict__ Wb,
               const __hip_bfloat16* __restrict__ Xt,
               void* __restrict__ Cout) {
    __shared__ __hip_bfloat16 As[64 * 32];
    __shared__ __hip_bfloat16 Bs[256 * 32];
    const int t = threadIdx.x;
    const int w = t >> 6, l = t & 63;
    const int lq = l >> 4, lr = l & 15;
    const int id = blockIdx.x;
    const int xj = id & 7;                 // XCD (dispatch round-robin)
    const int rest = id >> 3;
    const int m0 = (rest % MT) * 64;
    const int n0 = ((rest / MT) * 8 + xj) * 256;

    f32x4 acc[4][4] = {};

    for (int kt = 0; kt < 6; ++kt) {
        const int k0 = kt * 32;
        {
            int m = t >> 2, kc = t & 3;
            async_ld16(As + t * 8, Wb + (size_t)(m0 + m) * Cdim + k0 + kc * 8);
        }
#pragma unroll
        for (int it = 0; it < 4; ++it) {
            int idx = it * 256 + t;
            int n = idx >> 2, kc = idx & 3;
            const __hip_bfloat16* src;
            if (MODE == 0)
                src = Xt + (size_t)(n0 + n) * Cdim + k0 + kc * 8;
            else
                src = Xt + (size_t)kt * ((size_t)NTOT * 32) +
                      (size_t)(n0 + n) * 32 + kc * 8;
            async_ld16(Bs + idx * 8, src);
        }
        __syncthreads();

        short8 af[4], bf[4];
#pragma unroll
        for (int i = 0; i < 4; ++i)
            af[i] = *(const short8*)(void*)(As + (i * 16 + lr) * 32 + lq * 8);
#pragma unroll
        for (int j = 0; j < 4; ++j)
            bf[j] = *(const short8*)(void*)(Bs + (w * 64 + j * 16 + lr) * 32 + lq * 8);
#pragma unroll
        for (int i = 0; i < 4; ++i)
#pragma unroll
            for (int j = 0; j < 4; ++j)
                acc[i][j] = __builtin_amdgcn_mfma_f32_16x16x32_bf16(
                    af[i], bf[j], acc[i][j], 0, 0, 0);
        __syncthreads();
    }

    // epilogue: D col = lane&15, row = (lane>>4)*4 + r  (m89/m91-verified)
#pragma unroll
    for (int i = 0; i < 4; ++i) {
        int mb = m0 + i * 16 + lq * 4;            // 4 consecutive m (r=0..3)
#pragma unroll
        for (int j = 0; j < 4; ++j) {
            int n = n0 + w * 64 + j * 16 + lr;
            if (MODE == 0) {
                int three = mb / 192, rem = mb % 192;
                int pi = rem >> 6, pn = (rem >> 5) & 1, d4 = rem & 31;
                size_t plane = (size_t)((three * 3 + pi) * 2 + pn);
                __hip_bfloat16* dst = (__hip_bfloat16*)Cout +
                    plane * ((size_t)NTOT * 32) + (size_t)n * 32 + d4;
                short4v pk;
#pragma unroll
                for (int r = 0; r < 4; ++r) {
                    __hip_bfloat16 bv = __float2bfloat16(acc[i][j][r]);
                    pk[r] = *(short*)&bv;
                }
                *(short4v*)(void*)dst = pk;
            } else {
                int b = n >> 14, p = n & (HW - 1);
#pragma unroll
                for (int r = 0; r < 4; ++r)
                    ((float*)Cout)[((size_t)(b * Cdim + mb + r)) * HW + p] =
                        acc[i][j][r];
            }
        }
    }
}

// ---------------------------------------------------------------------------
// Attention, d-split: lane pair = one pixel, each lane owns 16 of 32 dims.
// Block = 1 image row (128 px x 2 slices). QKV/AO bf16 planes [*][NTOT][32].
// Latency-bound fix (this round): explicit load-all / compute-all phases.
//   phase 1: issue q + ALL 18 K 16B loads back-to-back (18 in flight/lane)
//   phase 2: dots; then issue ALL 18 V loads BEFORE softmax so the butterfly
//            + exp VALU work hides V latency.
// Peak regs ~110 (kx dead before vx live) -> fits 128 @ launch_bounds(256,4).
// XCD swizzle: each XCD gets 16 adjacent rows per (b,comb) -> K/V L2 reuse.
// ---------------------------------------------------------------------------
__global__ __launch_bounds__(256, 4)
void attn_kernel(const __hip_bfloat16* __restrict__ QKV,
                 __hip_bfloat16* __restrict__ AO) {
    int t = threadIdx.x;
    int pix = t >> 1, s = t & 1;
    int id = blockIdx.x;                 // 0..3071
    int xj = id & 7;                     // XCD
    int rest = id >> 3;                  // 0..383
    int cb = rest >> 4;                  // 0..23 = b*6 + comb
    int k16 = rest & 15;
    int h = xj * 16 + k16;               // image row 0..127
    int b = cb / 6, comb = cb % 6;
    int dil = (comb >> 1) + 1;

    int w = pix;
    int col = (b << 14) + h * Wdim + w;

    const size_t PS = (size_t)NTOT * 32;
    const __hip_bfloat16* Qp = QKV + (size_t)comb * PS;
    const __hip_bfloat16* Kp = Qp + 6 * PS;
    const __hip_bfloat16* Vp = Qp + 12 * PS;

    // reflect-padded dilated 3x3 neighborhood (within the b-th image)
    int cj[9];
#pragma unroll
    for (int kh = 0; kh < 3; ++kh) {
        int hh = h + (kh - 1) * dil;
        hh = hh < 0 ? -hh : (hh >= Hdim ? 2 * Hdim - 2 - hh : hh);
#pragma unroll
        for (int kw = 0; kw < 3; ++kw) {
            int ww = w + (kw - 1) * dil;
            ww = ww < 0 ? -ww : (ww >= Wdim ? 2 * Wdim - 2 - ww : ww);
            cj[kh * 3 + kw] = (b << 14) + hh * Wdim + ww;
        }
    }

    // ---- phase 1: issue q + ALL 18 K loads (independent; stay in flight) ----
    uint4 qv0, qv1;
    {
        const uint4* qp = (const uint4*)(Qp + (size_t)col * 32) + s * 2;
        qv0 = qp[0]; qv1 = qp[1];
    }
    uint4 kx[18];
#pragma unroll
    for (int j = 0; j < 9; ++j) {
        const uint4* kv = (const uint4*)(Kp + (size_t)cj[j] * 32) + s * 2;
        kx[2 * j]     = kv[0];
        kx[2 * j + 1] = kv[1];
    }

    // unpack q slice: 16 dims (global d = s*16 + 0..15)
    float q[16];
    {
        uint4 x = qv0;
        q[0] = lo16(x.x); q[1] = hi16(x.x);
        q[2] = lo16(x.y); q[3] = hi16(x.y);
        q[4] = lo16(x.z); q[5] = hi16(x.z);
        q[6] = lo16(x.w); q[7] = hi16(x.w);
        x = qv1;
        q[8]  = lo16(x.x); q[9]  = hi16(x.x);
        q[10] = lo16(x.y); q[11] = hi16(x.y);
        q[12] = lo16(x.z); q[13] = hi16(x.z);
        q[14] = lo16(x.w); q[15] = hi16(x.w);
    }

    // partial dots from registers (compiler inserts counted vmcnt waits)
    float sc[9];
#pragma unroll
    for (int j = 0; j < 9; ++j) {
        float p0 = 0.f;
        {
            uint4 x = kx[2 * j];
            p0 += q[0] * lo16(x.x) + q[1] * hi16(x.x);
            p0 += q[2] * lo16(x.y) + q[3] * hi16(x.y);
            p0 += q[4] * lo16(x.z) + q[5] * hi16(x.z);
            p0 += q[6] * lo16(x.w) + q[7] * hi16(x.w);
        }
        {
            uint4 x = kx[2 * j + 1];
            p0 += q[8]  * lo16(x.x) + q[9]  * hi16(x.x);
            p0 += q[10] * lo16(x.y) + q[11] * hi16(x.y);
            p0 += q[12] * lo16(x.z) + q[13] * hi16(x.z);
            p0 += q[14] * lo16(x.w) + q[15] * hi16(x.w);
        }
        sc[j] = p0;
    }

    // ---- phase 2: issue ALL 18 V loads BEFORE softmax VALU (hides latency) --
    uint4 vx[18];
#pragma unroll
    for (int j = 0; j < 9; ++j) {
        const uint4* vv = (const uint4*)(Vp + (size_t)cj[j] * 32) + s * 2;
        vx[2 * j]     = vv[0];
        vx[2 * j + 1] = vv[1];
    }

    // butterfly: both lanes of the pair get the full 32-d dot
#pragma unroll
    for (int j = 0; j < 9; ++j)
        sc[j] = (sc[j] + __shfl_xor(sc[j], 1, 64)) * 0.17677669529663687f;

    float m = sc[0];
#pragma unroll
    for (int j = 1; j < 9; ++j) m = fmaxf(m, sc[j]);
    float sum = 0.f;
#pragma unroll
    for (int j = 0; j < 9; ++j) { sc[j] = __expf(sc[j] - m); sum += sc[j]; }
    float inv = 1.f / sum;

    float acc[16] = {};
#pragma unroll
    for (int j = 0; j < 9; ++j) {
        float a = sc[j];
        {
            uint4 x = vx[2 * j];
            acc[0] += a * lo16(x.x); acc[1] += a * hi16(x.x);
            acc[2] += a * lo16(x.y); acc[3] += a * hi16(x.y);
            acc[4] += a * lo16(x.z); acc[5] += a * hi16(x.z);
            acc[6] += a * lo16(x.w); acc[7] += a * hi16(x.w);
        }
        {
            uint4 x = vx[2 * j + 1];
            acc[8]  += a * lo16(x.x); acc[9]  += a * hi16(x.x);
            acc[10] += a * lo16(x.y); acc[11] += a * hi16(x.y);
            acc[12] += a * lo16(x.z); acc[13] += a * hi16(x.z);
            acc[14] += a * lo16(x.w); acc[15] += a * hi16(x.w);
        }
    }

    // plane store: 32 B/thread, wave = 2 KB dense (full lines)
    union { unsigned short h[16]; short8 v[2]; } o;
#pragma unroll
    for (int d = 0; d < 16; ++d) {
        __hip_bfloat16 bv = __float2bfloat16(acc[d] * inv);
        o.h[d] = *(unsigned short*)&bv;
    }
    short8* dst = (short8*)(void*)(AO + (size_t)comb * PS + (size_t)col * 32 + s * 16);
#pragma unroll
    for (int u = 0; u < 2; ++u) dst[u] = o.v[u];
}

// ---------------------------------------------------------------------------
extern "C" void kernel_launch(void* const* d_in, const int* in_sizes, int n_in,
                              void* d_out, int out_size, void* d_ws, size_t ws_size,
                              hipStream_t stream) {
    const float* x      = (const float*)d_in[0];
    const float* pos_w  = (const float*)d_in[1];
    const float* pos_b  = (const float*)d_in[2];
    const float* qkv_w  = (const float*)d_in[3];
    const float* proj_w = (const float*)d_in[4];
    float* out = (float*)d_out;

    // ws layout (bytes): Xb 24 MiB | QKV planes 72 MiB | AO planes 24 MiB | Wq | Wp
    char* ws = (char*)d_ws;
    __hip_bfloat16* Xb  = (__hip_bfloat16*)ws;                            // [NTOT][192]
    __hip_bfloat16* QKV = (__hip_bfloat16*)(ws + (size_t)25165824);       // [18][NTOT][32]
    __hip_bfloat16* AO  = (__hip_bfloat16*)(ws + (size_t)100663296);      // [6][NTOT][32]
    __hip_bfloat16* Wq  = (__hip_bfloat16*)(ws + (size_t)125829120);      // [576][192]
    __hip_bfloat16* Wp  = (__hip_bfloat16*)(ws + (size_t)126050304);      // [192][192]

    convert_w<<<(QKVC * Cdim + Cdim * Cdim) / 256, 256, 0, stream>>>(
        qkv_w, proj_w, Wq, Wp);

    posconv_nhwc<<<NTOT / 64, 256, 0, stream>>>(x, pos_w, pos_b, Xb);

    gemm_mfma<0, 9><<<2304, 256, 0, stream>>>(Wq, Xb, QKV);

    attn_kernel<<<3072, 256, 0, stream>>>(QKV, AO);

    gemm_mfma<1, 3><<<768, 256, 0, stream>>>(Wp, AO, out);
}

// Round 2
// 205.724 us; speedup vs baseline: 1.2019x; 1.2019x over previous
//
#include <hip/hip_runtime.h>
#include <hip/hip_bf16.h>
#include <math.h>

// Problem constants (B=4, C=192, H=W=128, KS=3, dilations {1,2,3}, 6 heads)
#define Hdim 128
#define Wdim 128
#define HW   16384
#define Cdim 192
#define Bdim 4
#define QKVC 576            // 3*C
#define NTOT (Bdim * HW)    // 65536 total pixels

typedef __attribute__((ext_vector_type(8))) short short8;   // 8 bf16 (4 VGPRs)
typedef __attribute__((ext_vector_type(4))) short short4v;  // 4 bf16 (8 B)
typedef __attribute__((ext_vector_type(4))) float f32x4;

__device__ __forceinline__ void async_ld16(void* lds, const void* g) {
    __builtin_amdgcn_global_load_lds(
        (const __attribute__((address_space(1))) void*)g,
        (__attribute__((address_space(3))) void*)lds, 16, 0, 0);
}
__device__ __forceinline__ float lo16(unsigned u) { return __uint_as_float(u << 16); }
__device__ __forceinline__ float hi16(unsigned u) { return __uint_as_float(u & 0xffff0000u); }

// ---------------------------------------------------------------------------
// Convert both weight matrices to bf16 (147456 elements total).
// ---------------------------------------------------------------------------
__global__ void convert_w(const float* __restrict__ qkv_w,
                          const float* __restrict__ proj_w,
                          __hip_bfloat16* __restrict__ Wq,
                          __hip_bfloat16* __restrict__ Wp) {
    int i = blockIdx.x * 256 + threadIdx.x;
    if (i < QKVC * Cdim) {
        Wq[i] = __float2bfloat16(qkv_w[i]);
    } else {
        int j = i - QKVC * Cdim;
        Wp[j] = __float2bfloat16(proj_w[j]);
    }
}

// ---------------------------------------------------------------------------
// posconv: depthwise 3x3 (zero pad) + bias + residual, f32 NCHW in ->
// bf16 NHWC out [NTOT][192]. Block = 64-pixel half-row x 192 channels.
// ---------------------------------------------------------------------------
__global__ __launch_bounds__(256, 4)
void posconv_nhwc(const float* __restrict__ x,
                  const float* __restrict__ pos_w,
                  const float* __restrict__ pos_b,
                  __hip_bfloat16* __restrict__ Xb) {
    __shared__ __hip_bfloat16 tile[Cdim][68];   // [c][pixel], pad 64->68
    __shared__ float wts[Cdim * 9];
    __shared__ float bs[Cdim];
    int t = threadIdx.x;
    for (int i = t; i < Cdim * 9; i += 256) wts[i] = pos_w[i];
    if (t < Cdim) bs[t] = pos_b[t];
    __syncthreads();

    int p0 = blockIdx.x * 64;
    int b = p0 >> 14;
    int pimg = p0 & (HW - 1);
    int h = pimg >> 7, wbase = pimg & 127;      // 0 or 64
    const float* xim = x + (size_t)b * Cdim * HW;

#pragma unroll
    for (int it = 0; it < 12; ++it) {
        int quad = t & 15;
        int c = it * 16 + (t >> 4);
        int w0 = wbase + quad * 4;
        const float* xc = xim + (size_t)c * HW;
        const float* wt = wts + c * 9;
        float o0, o1, o2, o3;
        {   // center row: residual + bias + kh=1 taps
            const float* xr = xc + h * Wdim;
            float4 f = *(const float4*)(xr + w0);
            float L = (w0 > 0) ? xr[w0 - 1] : 0.f;
            float R = (w0 + 4 < Wdim) ? xr[w0 + 4] : 0.f;
            float b0 = bs[c];
            float w_0 = wt[3], w_1 = wt[4], w_2 = wt[5];
            o0 = f.x + b0 + w_0 * L   + w_1 * f.x + w_2 * f.y;
            o1 = f.y + b0 + w_0 * f.x + w_1 * f.y + w_2 * f.z;
            o2 = f.z + b0 + w_0 * f.y + w_1 * f.z + w_2 * f.w;
            o3 = f.w + b0 + w_0 * f.z + w_1 * f.w + w_2 * R;
        }
        if (h > 0) {   // row h-1, kh=0
            const float* xr = xc + (h - 1) * Wdim;
            float4 f = *(const float4*)(xr + w0);
            float L = (w0 > 0) ? xr[w0 - 1] : 0.f;
            float R = (w0 + 4 < Wdim) ? xr[w0 + 4] : 0.f;
            float w_0 = wt[0], w_1 = wt[1], w_2 = wt[2];
            o0 += w_0 * L   + w_1 * f.x + w_2 * f.y;
            o1 += w_0 * f.x + w_1 * f.y + w_2 * f.z;
            o2 += w_0 * f.y + w_1 * f.z + w_2 * f.w;
            o3 += w_0 * f.z + w_1 * f.w + w_2 * R;
        }
        if (h < Hdim - 1) {   // row h+1, kh=2
            const float* xr = xc + (h + 1) * Wdim;
            float4 f = *(const float4*)(xr + w0);
            float L = (w0 > 0) ? xr[w0 - 1] : 0.f;
            float R = (w0 + 4 < Wdim) ? xr[w0 + 4] : 0.f;
            float w_0 = wt[6], w_1 = wt[7], w_2 = wt[8];
            o0 += w_0 * L   + w_1 * f.x + w_2 * f.y;
            o1 += w_0 * f.x + w_1 * f.y + w_2 * f.z;
            o2 += w_0 * f.y + w_1 * f.z + w_2 * f.w;
            o3 += w_0 * f.z + w_1 * f.w + w_2 * R;
        }
        short4v pk;
        __hip_bfloat16 bv;
        bv = __float2bfloat16(o0); pk[0] = *(short*)&bv;
        bv = __float2bfloat16(o1); pk[1] = *(short*)&bv;
        bv = __float2bfloat16(o2); pk[2] = *(short*)&bv;
        bv = __float2bfloat16(o3); pk[3] = *(short*)&bv;
        *(short4v*)(void*)&tile[c][quad * 4] = pk;   // one ds_write_b64
    }
    __syncthreads();

    // phase 2: 1536 stores of 16B; lane = pixel (conflict-free LDS reads)
#pragma unroll
    for (int it = 0; it < 6; ++it) {
        int pl = t & 63;
        int cgq = it * 4 + (t >> 6);   // 0..23: channel octet
        union { unsigned short u[8]; short8 v; } o;
#pragma unroll
        for (int j = 0; j < 8; ++j)
            o.u[j] = *(const unsigned short*)&tile[cgq * 8 + j][pl];
        *(short8*)(void*)(Xb + (size_t)(p0 + pl) * Cdim + cgq * 8) = o.v;
    }
}

// ---------------------------------------------------------------------------
// MFMA bf16 GEMM: D[m,n] = sum_k W[m,k] * Xt[n,k]    (K = 192)
// Block 64x256 (4 waves of 64x64, 4x4 frags of 16x16x32). BK=32, 6 K-iters.
// 1-D grid, XCD-aware decode: each XCD runs all MT m-tiles of one n-block
// consecutively -> B-tile fetched into its L2 once, reused MT times.
// MODE 0: B = NHWC [NTOT][192]; store bf16 planes [(three*3+i)*2+nh][NTOT][32].
// MODE 1: B = planes [6][NTOT][32] (K-chunk kt == plane kt);
//         store f32 NCHW out[b][m][p], col n = b*HW + p.
// ---------------------------------------------------------------------------
template <int MODE, int MT>
__global__ __launch_bounds__(256, 2)
void gemm_mfma(const __hip_bfloat16* __restrict__ Wb,
               const __hip_bfloat16* __restrict__ Xt,
               void* __restrict__ Cout) {
    __shared__ __hip_bfloat16 As[64 * 32];
    __shared__ __hip_bfloat16 Bs[256 * 32];
    const int t = threadIdx.x;
    const int w = t >> 6, l = t & 63;
    const int lq = l >> 4, lr = l & 15;
    const int id = blockIdx.x;
    const int xj = id & 7;                 // XCD (dispatch round-robin)
    const int rest = id >> 3;
    const int m0 = (rest % MT) * 64;
    const int n0 = ((rest / MT) * 8 + xj) * 256;

    f32x4 acc[4][4] = {};

    for (int kt = 0; kt < 6; ++kt) {
        const int k0 = kt * 32;
        {
            int m = t >> 2, kc = t & 3;
            async_ld16(As + t * 8, Wb + (size_t)(m0 + m) * Cdim + k0 + kc * 8);
        }
#pragma unroll
        for (int it = 0; it < 4; ++it) {
            int idx = it * 256 + t;
            int n = idx >> 2, kc = idx & 3;
            const __hip_bfloat16* src;
            if (MODE == 0)
                src = Xt + (size_t)(n0 + n) * Cdim + k0 + kc * 8;
            else
                src = Xt + (size_t)kt * ((size_t)NTOT * 32) +
                      (size_t)(n0 + n) * 32 + kc * 8;
            async_ld16(Bs + idx * 8, src);
        }
        __syncthreads();

        short8 af[4], bf[4];
#pragma unroll
        for (int i = 0; i < 4; ++i)
            af[i] = *(const short8*)(void*)(As + (i * 16 + lr) * 32 + lq * 8);
#pragma unroll
        for (int j = 0; j < 4; ++j)
            bf[j] = *(const short8*)(void*)(Bs + (w * 64 + j * 16 + lr) * 32 + lq * 8);
#pragma unroll
        for (int i = 0; i < 4; ++i)
#pragma unroll
            for (int j = 0; j < 4; ++j)
                acc[i][j] = __builtin_amdgcn_mfma_f32_16x16x32_bf16(
                    af[i], bf[j], acc[i][j], 0, 0, 0);
        __syncthreads();
    }

    // epilogue: D col = lane&15, row = (lane>>4)*4 + r  (m89/m91-verified)
#pragma unroll
    for (int i = 0; i < 4; ++i) {
        int mb = m0 + i * 16 + lq * 4;            // 4 consecutive m (r=0..3)
#pragma unroll
        for (int j = 0; j < 4; ++j) {
            int n = n0 + w * 64 + j * 16 + lr;
            if (MODE == 0) {
                int three = mb / 192, rem = mb % 192;
                int pi = rem >> 6, pn = (rem >> 5) & 1, d4 = rem & 31;
                size_t plane = (size_t)((three * 3 + pi) * 2 + pn);
                __hip_bfloat16* dst = (__hip_bfloat16*)Cout +
                    plane * ((size_t)NTOT * 32) + (size_t)n * 32 + d4;
                short4v pk;
#pragma unroll
                for (int r = 0; r < 4; ++r) {
                    __hip_bfloat16 bv = __float2bfloat16(acc[i][j][r]);
                    pk[r] = *(short*)&bv;
                }
                *(short4v*)(void*)dst = pk;
            } else {
                int b = n >> 14, p = n & (HW - 1);
#pragma unroll
                for (int r = 0; r < 4; ++r)
                    ((float*)Cout)[((size_t)(b * Cdim + mb + r)) * HW + p] =
                        acc[i][j][r];
            }
        }
    }
}

// ---------------------------------------------------------------------------
// Attention, LDS-staged: block = one image row (128 px x 2 d-slices) of one
// (b, comb). K/V rows {h-d, h, h+d} (reflected) are DMA'd into LDS via
// global_load_lds (zero VGPR cost, all 3072 chunks in flight), then all 36
// neighbor reads per lane are ds_read_b128.
// Bank spread (rule 21: linear LDS dest + inverse-swizzled global SOURCE +
// swizzled READ): 16B-chunk involution  j <-> j ^ ((j>>3)&7)  spreads the 64
// lanes' read-starts uniformly over all 8 16B bank positions.
// XCD swizzle: each XCD gets 16 adjacent rows per (b,comb) -> K/V L2 reuse.
// ---------------------------------------------------------------------------
__global__ __launch_bounds__(256, 3)
void attn_kernel(const __hip_bfloat16* __restrict__ QKV,
                 __hip_bfloat16* __restrict__ AO) {
    __shared__ __align__(16) unsigned char lds[6][8192];  // K rows 0..2, V rows 3..5

    int t = threadIdx.x;
    int pix = t >> 1, s = t & 1;
    int id = blockIdx.x;                 // 0..3071
    int xj = id & 7;                     // XCD
    int rest = id >> 3;                  // 0..383
    int cb = rest >> 4;                  // 0..23 = b*6 + comb
    int k16 = rest & 15;
    int h = xj * 16 + k16;               // image row 0..127
    int b = cb / 6, comb = cb % 6;
    int dil = (comb >> 1) + 1;

    int w = pix;
    int col = (b << 14) + h * Wdim + w;

    const size_t PS = (size_t)NTOT * 32;
    const __hip_bfloat16* Qp = QKV + (size_t)comb * PS;
    const __hip_bfloat16* Kp = Qp + 6 * PS;
    const __hip_bfloat16* Vp = Qp + 12 * PS;

    // Q load issued first; its latency rides the stage barrier.
    const uint4* qp = (const uint4*)(Qp + (size_t)col * 32) + s * 2;
    uint4 qv0 = qp[0], qv1 = qp[1];

    // ---- stage K/V rows h-d, h, h+d (reflected) into LDS ----
    int hh[3];
#pragma unroll
    for (int kh = 0; kh < 3; ++kh) {
        int v = h + (kh - 1) * dil;
        hh[kh] = v < 0 ? -v : (v >= Hdim ? 2 * Hdim - 2 - v : v);
    }
    // thread t stages LDS chunks j0=t and j1=t+256 of each row; the source
    // chunk is the swizzle partner so a swizzled READ finds linear data.
    int j0 = t, j1 = t + 256;
    int g0 = j0 ^ ((j0 >> 3) & 7);
    int g1 = j1 ^ ((j1 >> 3) & 7);
#pragma unroll
    for (int r = 0; r < 3; ++r) {
        size_t rowe = ((size_t)(b << 14) + (size_t)hh[r] * Wdim) * 32;  // bf16 elems
        async_ld16(&lds[r][j0 * 16],     Kp + rowe + g0 * 8);
        async_ld16(&lds[r][j1 * 16],     Kp + rowe + g1 * 8);
        async_ld16(&lds[r + 3][j0 * 16], Vp + rowe + g0 * 8);
        async_ld16(&lds[r + 3][j1 * 16], Vp + rowe + g1 * 8);
    }
    __syncthreads();

    // unpack q slice: 16 dims (global d = s*16 + 0..15)
    float q[16];
    {
        uint4 x = qv0;
        q[0] = lo16(x.x); q[1] = hi16(x.x);
        q[2] = lo16(x.y); q[3] = hi16(x.y);
        q[4] = lo16(x.z); q[5] = hi16(x.z);
        q[6] = lo16(x.w); q[7] = hi16(x.w);
        x = qv1;
        q[8]  = lo16(x.x); q[9]  = hi16(x.x);
        q[10] = lo16(x.y); q[11] = hi16(x.y);
        q[12] = lo16(x.z); q[13] = hi16(x.z);
        q[14] = lo16(x.w); q[15] = hi16(x.w);
    }

    // neighbor byte offsets within a row buffer (first 16B chunk, swizzled)
    int coff[3];
#pragma unroll
    for (int kw = 0; kw < 3; ++kw) {
        int ww = w + (kw - 1) * dil;
        ww = ww < 0 ? -ww : (ww >= Wdim ? 2 * Wdim - 2 - ww : ww);
        int i0 = 4 * ww + 2 * s;               // linear chunk (d = s*16+0..7)
        coff[kw] = (i0 ^ ((ww >> 1) & 7)) * 16; // second chunk is coff ^ 16
    }

    // ---- scores: 18 ds_read_b128 + dots ----
    float sc[9];
#pragma unroll
    for (int kh = 0; kh < 3; ++kh)
#pragma unroll
        for (int kw = 0; kw < 3; ++kw) {
            uint4 xa = *(const uint4*)(void*)&lds[kh][coff[kw]];
            uint4 xb = *(const uint4*)(void*)&lds[kh][coff[kw] ^ 16];
            float p0 = 0.f;
            p0 += q[0] * lo16(xa.x) + q[1] * hi16(xa.x);
            p0 += q[2] * lo16(xa.y) + q[3] * hi16(xa.y);
            p0 += q[4] * lo16(xa.z) + q[5] * hi16(xa.z);
            p0 += q[6] * lo16(xa.w) + q[7] * hi16(xa.w);
            p0 += q[8]  * lo16(xb.x) + q[9]  * hi16(xb.x);
            p0 += q[10] * lo16(xb.y) + q[11] * hi16(xb.y);
            p0 += q[12] * lo16(xb.z) + q[13] * hi16(xb.z);
            p0 += q[14] * lo16(xb.w) + q[15] * hi16(xb.w);
            sc[kh * 3 + kw] = p0;
        }

    // butterfly: both lanes of the pair get the full 32-d dot
#pragma unroll
    for (int j = 0; j < 9; ++j)
        sc[j] = (sc[j] + __shfl_xor(sc[j], 1, 64)) * 0.17677669529663687f;

    float m = sc[0];
#pragma unroll
    for (int j = 1; j < 9; ++j) m = fmaxf(m, sc[j]);
    float sum = 0.f;
#pragma unroll
    for (int j = 0; j < 9; ++j) { sc[j] = __expf(sc[j] - m); sum += sc[j]; }
    float inv = 1.f / sum;

    // ---- PV: 18 ds_read_b128 + weighted accumulate ----
    float acc[16] = {};
#pragma unroll
    for (int kh = 0; kh < 3; ++kh)
#pragma unroll
        for (int kw = 0; kw < 3; ++kw) {
            float a = sc[kh * 3 + kw];
            uint4 xa = *(const uint4*)(void*)&lds[kh + 3][coff[kw]];
            uint4 xb = *(const uint4*)(void*)&lds[kh + 3][coff[kw] ^ 16];
            acc[0] += a * lo16(xa.x); acc[1] += a * hi16(xa.x);
            acc[2] += a * lo16(xa.y); acc[3] += a * hi16(xa.y);
            acc[4] += a * lo16(xa.z); acc[5] += a * hi16(xa.z);
            acc[6] += a * lo16(xa.w); acc[7] += a * hi16(xa.w);
            acc[8]  += a * lo16(xb.x); acc[9]  += a * hi16(xb.x);
            acc[10] += a * lo16(xb.y); acc[11] += a * hi16(xb.y);
            acc[12] += a * lo16(xb.z); acc[13] += a * hi16(xb.z);
            acc[14] += a * lo16(xb.w); acc[15] += a * hi16(xb.w);
        }

    // plane store: 32 B/thread, wave = 2 KB dense (full lines)
    union { unsigned short hu[16]; short8 v[2]; } o;
#pragma unroll
    for (int d = 0; d < 16; ++d) {
        __hip_bfloat16 bv = __float2bfloat16(acc[d] * inv);
        o.hu[d] = *(unsigned short*)&bv;
    }
    short8* dst = (short8*)(void*)(AO + (size_t)comb * PS + (size_t)col * 32 + s * 16);
#pragma unroll
    for (int u = 0; u < 2; ++u) dst[u] = o.v[u];
}

// ---------------------------------------------------------------------------
extern "C" void kernel_launch(void* const* d_in, const int* in_sizes, int n_in,
                              void* d_out, int out_size, void* d_ws, size_t ws_size,
                              hipStream_t stream) {
    const float* x      = (const float*)d_in[0];
    const float* pos_w  = (const float*)d_in[1];
    const float* pos_b  = (const float*)d_in[2];
    const float* qkv_w  = (const float*)d_in[3];
    const float* proj_w = (const float*)d_in[4];
    float* out = (float*)d_out;

    // ws layout (bytes): Xb 24 MiB | QKV planes 72 MiB | AO planes 24 MiB | Wq | Wp
    char* ws = (char*)d_ws;
    __hip_bfloat16* Xb  = (__hip_bfloat16*)ws;                            // [NTOT][192]
    __hip_bfloat16* QKV = (__hip_bfloat16*)(ws + (size_t)25165824);       // [18][NTOT][32]
    __hip_bfloat16* AO  = (__hip_bfloat16*)(ws + (size_t)100663296);      // [6][NTOT][32]
    __hip_bfloat16* Wq  = (__hip_bfloat16*)(ws + (size_t)125829120);      // [576][192]
    __hip_bfloat16* Wp  = (__hip_bfloat16*)(ws + (size_t)126050304);      // [192][192]

    convert_w<<<(QKVC * Cdim + Cdim * Cdim) / 256, 256, 0, stream>>>(
        qkv_w, proj_w, Wq, Wp);

    posconv_nhwc<<<NTOT / 64, 256, 0, stream>>>(x, pos_w, pos_b, Xb);

    gemm_mfma<0, 9><<<2304, 256, 0, stream>>>(Wq, Xb, QKV);

    attn_kernel<<<3072, 256, 0, stream>>>(QKV, AO);

    gemm_mfma<1, 3><<<768, 256, 0, stream>>>(Wp, AO, out);
}

// Round 4
// 203.656 us; speedup vs baseline: 1.2141x; 1.0102x over previous
//
#include <hip/hip_runtime.h>
#include <hip/hip_bf16.h>
#include <math.h>

// Problem constants (B=4, C=192, H=W=128, KS=3, dilations {1,2,3}, 6 heads)
#define Hdim 128
#define Wdim 128
#define HW   16384
#define Cdim 192
#define Bdim 4
#define QKVC 576            // 3*C
#define NTOT (Bdim * HW)    // 65536 total pixels

typedef __attribute__((ext_vector_type(8))) short short8;   // 8 bf16 (4 VGPRs)
typedef __attribute__((ext_vector_type(4))) short short4v;  // 4 bf16 (8 B)
typedef __attribute__((ext_vector_type(4))) float f32x4;

__device__ __forceinline__ void async_ld16(void* lds, const void* g) {
    __builtin_amdgcn_global_load_lds(
        (const __attribute__((address_space(1))) void*)g,
        (__attribute__((address_space(3))) void*)lds, 16, 0, 0);
}
__device__ __forceinline__ float lo16(unsigned u) { return __uint_as_float(u << 16); }
__device__ __forceinline__ float hi16(unsigned u) { return __uint_as_float(u & 0xffff0000u); }

// ---------------------------------------------------------------------------
// Convert both weight matrices to bf16 (147456 elements total).
// ---------------------------------------------------------------------------
__global__ void convert_w(const float* __restrict__ qkv_w,
                          const float* __restrict__ proj_w,
                          __hip_bfloat16* __restrict__ Wq,
                          __hip_bfloat16* __restrict__ Wp) {
    int i = blockIdx.x * 256 + threadIdx.x;
    if (i < QKVC * Cdim) {
        Wq[i] = __float2bfloat16(qkv_w[i]);
    } else {
        int j = i - QKVC * Cdim;
        Wp[j] = __float2bfloat16(proj_w[j]);
    }
}

// ---------------------------------------------------------------------------
// posconv: depthwise 3x3 (zero pad) + bias + residual, f32 NCHW in ->
// bf16 NHWC out [NTOT][192]. Block = 64-pixel half-row x 192 channels.
// XCD band decode: XCD j owns rows [16j,16j+16) of every image, so the h+-1
// vertical-halo rows AND the L/R column-halo lines are re-read by blocks on
// the SAME XCD -> L2 hits instead of cross-XCD L3/HBM misses.
// ---------------------------------------------------------------------------
__global__ __launch_bounds__(256, 4)
void posconv_nhwc(const float* __restrict__ x,
                  const float* __restrict__ pos_w,
                  const float* __restrict__ pos_b,
                  __hip_bfloat16* __restrict__ Xb) {
    __shared__ __hip_bfloat16 tile[Cdim][68];   // [c][pixel], pad 64->68
    __shared__ float wts[Cdim * 9];
    __shared__ float bs[Cdim];
    int t = threadIdx.x;
    for (int i = t; i < Cdim * 9; i += 256) wts[i] = pos_w[i];
    if (t < Cdim) bs[t] = pos_b[t];
    __syncthreads();

    // XCD-banded decode: id -> (xj band, image, row-in-band, half)
    int id = blockIdx.x;                 // 0..1023
    int xj = id & 7;                     // XCD (dispatch round-robin)
    int r  = id >> 3;                    // 0..127
    int b  = r >> 5;                     // image 0..3
    int k  = r & 31;                     // 0..31
    int h  = xj * 16 + (k >> 1);         // row: each XCD a 16-row band
    int wbase = (k & 1) * 64;            // half-row 0 or 64
    int p0 = (b << 14) + h * Wdim + wbase;
    const float* xim = x + (size_t)b * Cdim * HW;

#pragma unroll
    for (int it = 0; it < 12; ++it) {
        int quad = t & 15;
        int c = it * 16 + (t >> 4);
        int w0 = wbase + quad * 4;
        const float* xc = xim + (size_t)c * HW;
        const float* wt = wts + c * 9;
        float o0, o1, o2, o3;
        {   // center row: residual + bias + kh=1 taps
            const float* xr = xc + h * Wdim;
            float4 f = *(const float4*)(xr + w0);
            float L = (w0 > 0) ? xr[w0 - 1] : 0.f;
            float R = (w0 + 4 < Wdim) ? xr[w0 + 4] : 0.f;
            float b0 = bs[c];
            float w_0 = wt[3], w_1 = wt[4], w_2 = wt[5];
            o0 = f.x + b0 + w_0 * L   + w_1 * f.x + w_2 * f.y;
            o1 = f.y + b0 + w_0 * f.x + w_1 * f.y + w_2 * f.z;
            o2 = f.z + b0 + w_0 * f.y + w_1 * f.z + w_2 * f.w;
            o3 = f.w + b0 + w_0 * f.z + w_1 * f.w + w_2 * R;
        }
        if (h > 0) {   // row h-1, kh=0
            const float* xr = xc + (h - 1) * Wdim;
            float4 f = *(const float4*)(xr + w0);
            float L = (w0 > 0) ? xr[w0 - 1] : 0.f;
            float R = (w0 + 4 < Wdim) ? xr[w0 + 4] : 0.f;
            float w_0 = wt[0], w_1 = wt[1], w_2 = wt[2];
            o0 += w_0 * L   + w_1 * f.x + w_2 * f.y;
            o1 += w_0 * f.x + w_1 * f.y + w_2 * f.z;
            o2 += w_0 * f.y + w_1 * f.z + w_2 * f.w;
            o3 += w_0 * f.z + w_1 * f.w + w_2 * R;
        }
        if (h < Hdim - 1) {   // row h+1, kh=2
            const float* xr = xc + (h + 1) * Wdim;
            float4 f = *(const float4*)(xr + w0);
            float L = (w0 > 0) ? xr[w0 - 1] : 0.f;
            float R = (w0 + 4 < Wdim) ? xr[w0 + 4] : 0.f;
            float w_0 = wt[6], w_1 = wt[7], w_2 = wt[8];
            o0 += w_0 * L   + w_1 * f.x + w_2 * f.y;
            o1 += w_0 * f.x + w_1 * f.y + w_2 * f.z;
            o2 += w_0 * f.y + w_1 * f.z + w_2 * f.w;
            o3 += w_0 * f.z + w_1 * f.w + w_2 * R;
        }
        short4v pk;
        __hip_bfloat16 bv;
        bv = __float2bfloat16(o0); pk[0] = *(short*)&bv;
        bv = __float2bfloat16(o1); pk[1] = *(short*)&bv;
        bv = __float2bfloat16(o2); pk[2] = *(short*)&bv;
        bv = __float2bfloat16(o3); pk[3] = *(short*)&bv;
        *(short4v*)(void*)&tile[c][quad * 4] = pk;   // one ds_write_b64
    }
    __syncthreads();

    // phase 2: 1536 stores of 16B; lane = pixel (conflict-free LDS reads)
#pragma unroll
    for (int it = 0; it < 6; ++it) {
        int pl = t & 63;
        int cgq = it * 4 + (t >> 6);   // 0..23: channel octet
        union { unsigned short u[8]; short8 v; } o;
#pragma unroll
        for (int j = 0; j < 8; ++j)
            o.u[j] = *(const unsigned short*)&tile[cgq * 8 + j][pl];
        *(short8*)(void*)(Xb + (size_t)(p0 + pl) * Cdim + cgq * 8) = o.v;
    }
}

// ---------------------------------------------------------------------------
// MFMA bf16 GEMM: D[m,n] = sum_k W[m,k] * Xt[n,k]    (K = 192)
// Block 64x256 (4 waves of 64x64, 4x4 frags of 16x16x32). BK=32, 6 K-iters.
// 1-D grid, XCD-aware decode: each XCD runs all MT m-tiles of one n-block
// consecutively -> B-tile fetched into its L2 once, reused MT times.
// MODE 0: B = NHWC [NTOT][192]; store bf16 planes [(three*3+i)*2+nh][NTOT][32].
// MODE 1: B = planes [6][NTOT][32] (K-chunk kt == plane kt);
//         store f32 NCHW out[b][m][p], col n = b*HW + p.
// ---------------------------------------------------------------------------
template <int MODE, int MT>
__global__ __launch_bounds__(256, 2)
void gemm_mfma(const __hip_bfloat16* __restrict__ Wb,
               const __hip_bfloat16* __restrict__ Xt,
               void* __restrict__ Cout) {
    __shared__ __hip_bfloat16 As[64 * 32];
    __shared__ __hip_bfloat16 Bs[256 * 32];
    const int t = threadIdx.x;
    const int w = t >> 6, l = t & 63;
    const int lq = l >> 4, lr = l & 15;
    const int id = blockIdx.x;
    const int xj = id & 7;                 // XCD (dispatch round-robin)
    const int rest = id >> 3;
    const int m0 = (rest % MT) * 64;
    const int n0 = ((rest / MT) * 8 + xj) * 256;

    f32x4 acc[4][4] = {};

    for (int kt = 0; kt < 6; ++kt) {
        const int k0 = kt * 32;
        {
            int m = t >> 2, kc = t & 3;
            async_ld16(As + t * 8, Wb + (size_t)(m0 + m) * Cdim + k0 + kc * 8);
        }
#pragma unroll
        for (int it = 0; it < 4; ++it) {
            int idx = it * 256 + t;
            int n = idx >> 2, kc = idx & 3;
            const __hip_bfloat16* src;
            if (MODE == 0)
                src = Xt + (size_t)(n0 + n) * Cdim + k0 + kc * 8;
            else
                src = Xt + (size_t)kt * ((size_t)NTOT * 32) +
                      (size_t)(n0 + n) * 32 + kc * 8;
            async_ld16(Bs + idx * 8, src);
        }
        __syncthreads();

        short8 af[4], bf[4];
#pragma unroll
        for (int i = 0; i < 4; ++i)
            af[i] = *(const short8*)(void*)(As + (i * 16 + lr) * 32 + lq * 8);
#pragma unroll
        for (int j = 0; j < 4; ++j)
            bf[j] = *(const short8*)(void*)(Bs + (w * 64 + j * 16 + lr) * 32 + lq * 8);
#pragma unroll
        for (int i = 0; i < 4; ++i)
#pragma unroll
            for (int j = 0; j < 4; ++j)
                acc[i][j] = __builtin_amdgcn_mfma_f32_16x16x32_bf16(
                    af[i], bf[j], acc[i][j], 0, 0, 0);
        __syncthreads();
    }

    // epilogue: D col = lane&15, row = (lane>>4)*4 + r  (m89/m91-verified)
#pragma unroll
    for (int i = 0; i < 4; ++i) {
        int mb = m0 + i * 16 + lq * 4;            // 4 consecutive m (r=0..3)
#pragma unroll
        for (int j = 0; j < 4; ++j) {
            int n = n0 + w * 64 + j * 16 + lr;
            if (MODE == 0) {
                int three = mb / 192, rem = mb % 192;
                int pi = rem >> 6, pn = (rem >> 5) & 1, d4 = rem & 31;
                size_t plane = (size_t)((three * 3 + pi) * 2 + pn);
                __hip_bfloat16* dst = (__hip_bfloat16*)Cout +
                    plane * ((size_t)NTOT * 32) + (size_t)n * 32 + d4;
                short4v pk;
#pragma unroll
                for (int r = 0; r < 4; ++r) {
                    __hip_bfloat16 bv = __float2bfloat16(acc[i][j][r]);
                    pk[r] = *(short*)&bv;
                }
                *(short4v*)(void*)dst = pk;
            } else {
                int b = n >> 14, p = n & (HW - 1);
#pragma unroll
                for (int r = 0; r < 4; ++r)
                    ((float*)Cout)[((size_t)(b * Cdim + mb + r)) * HW + p] =
                        acc[i][j][r];
            }
        }
    }
}

// ---------------------------------------------------------------------------
// Attention, LDS-staged: block = one image row (128 px x 2 d-slices) of one
// (b, comb). K/V rows {h-d, h, h+d} (reflected) are DMA'd into LDS via
// global_load_lds (zero VGPR cost, all 3072 chunks in flight), then all 36
// neighbor reads per lane are ds_read_b128.
// Bank spread (rule 21: linear LDS dest + inverse-swizzled global SOURCE +
// swizzled READ): 16B-chunk involution  j <-> j ^ ((j>>3)&7)  spreads the 64
// lanes' read-starts uniformly over all 8 16B bank positions.
// XCD swizzle: each XCD gets 16 adjacent rows per (b,comb) -> K/V L2 reuse.
// ---------------------------------------------------------------------------
__global__ __launch_bounds__(256, 3)
void attn_kernel(const __hip_bfloat16* __restrict__ QKV,
                 __hip_bfloat16* __restrict__ AO) {
    __shared__ __align__(16) unsigned char lds[6][8192];  // K rows 0..2, V rows 3..5

    int t = threadIdx.x;
    int pix = t >> 1, s = t & 1;
    int id = blockIdx.x;                 // 0..3071
    int xj = id & 7;                     // XCD
    int rest = id >> 3;                  // 0..383
    int cb = rest >> 4;                  // 0..23 = b*6 + comb
    int k16 = rest & 15;
    int h = xj * 16 + k16;               // image row 0..127
    int b = cb / 6, comb = cb % 6;
    int dil = (comb >> 1) + 1;

    int w = pix;
    int col = (b << 14) + h * Wdim + w;

    const size_t PS = (size_t)NTOT * 32;
    const __hip_bfloat16* Qp = QKV + (size_t)comb * PS;
    const __hip_bfloat16* Kp = Qp + 6 * PS;
    const __hip_bfloat16* Vp = Qp + 12 * PS;

    // Q load issued first; its latency rides the stage barrier.
    const uint4* qp = (const uint4*)(Qp + (size_t)col * 32) + s * 2;
    uint4 qv0 = qp[0], qv1 = qp[1];

    // ---- stage K/V rows h-d, h, h+d (reflected) into LDS ----
    int hh[3];
#pragma unroll
    for (int kh = 0; kh < 3; ++kh) {
        int v = h + (kh - 1) * dil;
        hh[kh] = v < 0 ? -v : (v >= Hdim ? 2 * Hdim - 2 - v : v);
    }
    // thread t stages LDS chunks j0=t and j1=t+256 of each row; the source
    // chunk is the swizzle partner so a swizzled READ finds linear data.
    int j0 = t, j1 = t + 256;
    int g0 = j0 ^ ((j0 >> 3) & 7);
    int g1 = j1 ^ ((j1 >> 3) & 7);
#pragma unroll
    for (int r = 0; r < 3; ++r) {
        size_t rowe = ((size_t)(b << 14) + (size_t)hh[r] * Wdim) * 32;  // bf16 elems
        async_ld16(&lds[r][j0 * 16],     Kp + rowe + g0 * 8);
        async_ld16(&lds[r][j1 * 16],     Kp + rowe + g1 * 8);
        async_ld16(&lds[r + 3][j0 * 16], Vp + rowe + g0 * 8);
        async_ld16(&lds[r + 3][j1 * 16], Vp + rowe + g1 * 8);
    }
    __syncthreads();

    // unpack q slice: 16 dims (global d = s*16 + 0..15)
    float q[16];
    {
        uint4 x = qv0;
        q[0] = lo16(x.x); q[1] = hi16(x.x);
        q[2] = lo16(x.y); q[3] = hi16(x.y);
        q[4] = lo16(x.z); q[5] = hi16(x.z);
        q[6] = lo16(x.w); q[7] = hi16(x.w);
        x = qv1;
        q[8]  = lo16(x.x); q[9]  = hi16(x.x);
        q[10] = lo16(x.y); q[11] = hi16(x.y);
        q[12] = lo16(x.z); q[13] = hi16(x.z);
        q[14] = lo16(x.w); q[15] = hi16(x.w);
    }

    // neighbor byte offsets within a row buffer (first 16B chunk, swizzled)
    int coff[3];
#pragma unroll
    for (int kw = 0; kw < 3; ++kw) {
        int ww = w + (kw - 1) * dil;
        ww = ww < 0 ? -ww : (ww >= Wdim ? 2 * Wdim - 2 - ww : ww);
        int i0 = 4 * ww + 2 * s;               // linear chunk (d = s*16+0..7)
        coff[kw] = (i0 ^ ((ww >> 1) & 7)) * 16; // second chunk is coff ^ 16
    }

    // ---- scores: 18 ds_read_b128 + dots ----
    float sc[9];
#pragma unroll
    for (int kh = 0; kh < 3; ++kh)
#pragma unroll
        for (int kw = 0; kw < 3; ++kw) {
            uint4 xa = *(const uint4*)(void*)&lds[kh][coff[kw]];
            uint4 xb = *(const uint4*)(void*)&lds[kh][coff[kw] ^ 16];
            float p0 = 0.f;
            p0 += q[0] * lo16(xa.x) + q[1] * hi16(xa.x);
            p0 += q[2] * lo16(xa.y) + q[3] * hi16(xa.y);
            p0 += q[4] * lo16(xa.z) + q[5] * hi16(xa.z);
            p0 += q[6] * lo16(xa.w) + q[7] * hi16(xa.w);
            p0 += q[8]  * lo16(xb.x) + q[9]  * hi16(xb.x);
            p0 += q[10] * lo16(xb.y) + q[11] * hi16(xb.y);
            p0 += q[12] * lo16(xb.z) + q[13] * hi16(xb.z);
            p0 += q[14] * lo16(xb.w) + q[15] * hi16(xb.w);
            sc[kh * 3 + kw] = p0;
        }

    // butterfly: both lanes of the pair get the full 32-d dot
#pragma unroll
    for (int j = 0; j < 9; ++j)
        sc[j] = (sc[j] + __shfl_xor(sc[j], 1, 64)) * 0.17677669529663687f;

    float m = sc[0];
#pragma unroll
    for (int j = 1; j < 9; ++j) m = fmaxf(m, sc[j]);
    float sum = 0.f;
#pragma unroll
    for (int j = 0; j < 9; ++j) { sc[j] = __expf(sc[j] - m); sum += sc[j]; }
    float inv = 1.f / sum;

    // ---- PV: 18 ds_read_b128 + weighted accumulate ----
    float acc[16] = {};
#pragma unroll
    for (int kh = 0; kh < 3; ++kh)
#pragma unroll
        for (int kw = 0; kw < 3; ++kw) {
            float a = sc[kh * 3 + kw];
            uint4 xa = *(const uint4*)(void*)&lds[kh + 3][coff[kw]];
            uint4 xb = *(const uint4*)(void*)&lds[kh + 3][coff[kw] ^ 16];
            acc[0] += a * lo16(xa.x); acc[1] += a * hi16(xa.x);
            acc[2] += a * lo16(xa.y); acc[3] += a * hi16(xa.y);
            acc[4] += a * lo16(xa.z); acc[5] += a * hi16(xa.z);
            acc[6] += a * lo16(xa.w); acc[7] += a * hi16(xa.w);
            acc[8]  += a * lo16(xb.x); acc[9]  += a * hi16(xb.x);
            acc[10] += a * lo16(xb.y); acc[11] += a * hi16(xb.y);
            acc[12] += a * lo16(xb.z); acc[13] += a * hi16(xb.z);
            acc[14] += a * lo16(xb.w); acc[15] += a * hi16(xb.w);
        }

    // plane store: 32 B/thread, wave = 2 KB dense (full lines)
    union { unsigned short hu[16]; short8 v[2]; } o;
#pragma unroll
    for (int d = 0; d < 16; ++d) {
        __hip_bfloat16 bv = __float2bfloat16(acc[d] * inv);
        o.hu[d] = *(unsigned short*)&bv;
    }
    short8* dst = (short8*)(void*)(AO + (size_t)comb * PS + (size_t)col * 32 + s * 16);
#pragma unroll
    for (int u = 0; u < 2; ++u) dst[u] = o.v[u];
}

// ---------------------------------------------------------------------------
extern "C" void kernel_launch(void* const* d_in, const int* in_sizes, int n_in,
                              void* d_out, int out_size, void* d_ws, size_t ws_size,
                              hipStream_t stream) {
    const float* x      = (const float*)d_in[0];
    const float* pos_w  = (const float*)d_in[1];
    const float* pos_b  = (const float*)d_in[2];
    const float* qkv_w  = (const float*)d_in[3];
    const float* proj_w = (const float*)d_in[4];
    float* out = (float*)d_out;

    // ws layout (bytes): Xb 24 MiB | QKV planes 72 MiB | AO planes 24 MiB | Wq | Wp
    char* ws = (char*)d_ws;
    __hip_bfloat16* Xb  = (__hip_bfloat16*)ws;                            // [NTOT][192]
    __hip_bfloat16* QKV = (__hip_bfloat16*)(ws + (size_t)25165824);       // [18][NTOT][32]
    __hip_bfloat16* AO  = (__hip_bfloat16*)(ws + (size_t)100663296);      // [6][NTOT][32]
    __hip_bfloat16* Wq  = (__hip_bfloat16*)(ws + (size_t)125829120);      // [576][192]
    __hip_bfloat16* Wp  = (__hip_bfloat16*)(ws + (size_t)126050304);      // [192][192]

    convert_w<<<(QKVC * Cdim + Cdim * Cdim) / 256, 256, 0, stream>>>(
        qkv_w, proj_w, Wq, Wp);

    posconv_nhwc<<<NTOT / 64, 256, 0, stream>>>(x, pos_w, pos_b, Xb);

    gemm_mfma<0, 9><<<2304, 256, 0, stream>>>(Wq, Xb, QKV);

    attn_kernel<<<3072, 256, 0, stream>>>(QKV, AO);

    gemm_mfma<1, 3><<<768, 256, 0, stream>>>(Wp, AO, out);
}

// Round 5
// 187.421 us; speedup vs baseline: 1.3193x; 1.0866x over previous
//
#include <hip/hip_runtime.h>
#include <hip/hip_bf16.h>
#include <math.h>

// Problem constants (B=4, C=192, H=W=128, KS=3, dilations {1,2,3}, 6 heads)
#define Hdim 128
#define Wdim 128
#define HW   16384
#define Cdim 192
#define Bdim 4
#define QKVC 576            // 3*C
#define NTOT (Bdim * HW)    // 65536 total pixels

typedef __attribute__((ext_vector_type(8))) short short8;   // 8 bf16 (4 VGPRs)
typedef __attribute__((ext_vector_type(4))) short short4v;  // 4 bf16 (8 B)
typedef __attribute__((ext_vector_type(4))) float f32x4;

__device__ __forceinline__ void async_ld16(void* lds, const void* g) {
    __builtin_amdgcn_global_load_lds(
        (const __attribute__((address_space(1))) void*)g,
        (__attribute__((address_space(3))) void*)lds, 16, 0, 0);
}
__device__ __forceinline__ float lo16(unsigned u) { return __uint_as_float(u << 16); }
__device__ __forceinline__ float hi16(unsigned u) { return __uint_as_float(u & 0xffff0000u); }

// ---------------------------------------------------------------------------
// Convert both weight matrices to bf16 (147456 elements total).
// ---------------------------------------------------------------------------
__global__ void convert_w(const float* __restrict__ qkv_w,
                          const float* __restrict__ proj_w,
                          __hip_bfloat16* __restrict__ Wq,
                          __hip_bfloat16* __restrict__ Wp) {
    int i = blockIdx.x * 256 + threadIdx.x;
    if (i < QKVC * Cdim) {
        Wq[i] = __float2bfloat16(qkv_w[i]);
    } else {
        int j = i - QKVC * Cdim;
        Wp[j] = __float2bfloat16(proj_w[j]);
    }
}

// ---------------------------------------------------------------------------
// posconv v2: depthwise 3x3 (zero pad) + bias + residual, f32 NCHW in ->
// bf16 NHWC out [NTOT][192].
// Block = (image b, row h, 16-channel group cg); grid 6144 (6x parallelism).
// Rows {h-1,h,h+1} x 16 ch x 128 px staged to LDS via global_load_lds (bulk
// DMA, zero VGPR payload). Rule 21: linear LDS dest + chunk-swizzled global
// SOURCE (q ^= ch, involution) + same XOR on ds_read -> 8-phase floor
// (unswizzled would be 16-way bank conflict: ch-row stride 512B = bank+0).
// Each thread: 8-px span of one channel; L/R via shfl (block = full row, so
// span edges at image edge = zero-pad -> NO edge loads). Top/bottom zero-pad
// via per-row weight masks. XCD banding: consecutive same-XCD blocks =
// consecutive rows of same cg -> 2 of 3 staged rows are L2 hits.
// ---------------------------------------------------------------------------
__global__ __launch_bounds__(256, 5)
void posconv_nhwc(const float* __restrict__ x,
                  const float* __restrict__ pos_w,
                  const float* __restrict__ pos_b,
                  __hip_bfloat16* __restrict__ Xb) {
    __shared__ __align__(16) float xs[3 * 16 * 128];      // 24 KB staged rows
    __shared__ __hip_bfloat16 tile[16][132];              // transpose tile

    int t = threadIdx.x;
    int id = blockIdx.x;                 // 0..6143
    int xj = id & 7;                     // XCD (dispatch round-robin)
    int r_ = id >> 3;                    // 0..767
    int rb = r_ & 15;
    int cg = (r_ >> 4) % 12;             // channel group 0..11
    int b  = (r_ >> 4) / 12;             // image 0..3
    int h  = xj * 16 + rb;               // row 0..127 (16-row band per XCD)

    // clamped stencil rows (zero-pad handled by weight masks below)
    int hm = h > 0 ? h - 1 : 0;
    int hp = h < Hdim - 1 ? h + 1 : Hdim - 1;
    int hh0 = hm, hh1 = h, hh2 = hp;

    // per-thread channel & span
    int ch = t >> 4;                     // 0..15 within group
    int qh = t & 15;                     // 8-px span index
    int cglob = cg * 16 + ch;

    // ---- issue weight/bias loads (uniform per 16-lane group; L1/L2 cached)
    const float* wp = pos_w + cglob * 9;
    float w0 = wp[0], w1 = wp[1], w2 = wp[2];
    float w3 = wp[3], w4 = wp[4], w5 = wp[5];
    float w6 = wp[6], w7 = wp[7], w8 = wp[8];
    float bias = pos_b[cglob];
    float m0 = (h > 0) ? 1.f : 0.f;
    float m2 = (h < Hdim - 1) ? 1.f : 0.f;
    w0 *= m0; w1 *= m0; w2 *= m0;
    w6 *= m2; w7 *= m2; w8 *= m2;

    // ---- stage 3 rows x 16 ch x 128 px (1536 chunks of 16B, 6/thread) ----
    // LDS chunk u holds source chunk (u&31)^ch of row (u>>5) -> read with XOR.
    {
        const float* xg = x + (size_t)(b * Cdim + cg * 16) * HW;
#pragma unroll
        for (int k = 0; k < 6; ++k) {
            int u = t + k * 256;
            int rowi = u >> 5;           // 0..47 = r*16 + sch
            int ql = u & 31;
            int rr = rowi >> 4;
            int sch = rowi & 15;
            int hr = rr == 0 ? hh0 : (rr == 1 ? hh1 : hh2);
            int qs = ql ^ sch;           // swizzle involution
            async_ld16((char*)xs + (size_t)u * 16,
                       xg + (size_t)sch * HW + hr * Wdim + qs * 4);
        }
    }
    __syncthreads();

    // ---- compute 8 outputs (px p0..p0+7), reading swizzled LDS ----
    float out[8];
    const char* xsb = (const char*)xs;
#pragma unroll
    for (int rr = 0; rr < 3; ++rr) {
        const char* rowb = xsb + (size_t)(rr * 16 + ch) * 512;
        float4 lo = *(const float4*)(rowb + (((2 * qh)     ^ ch) * 16));
        float4 hi = *(const float4*)(rowb + (((2 * qh + 1) ^ ch) * 16));
        float L = __shfl_up(hi.w, 1, 64);
        float R = __shfl_down(lo.x, 1, 64);
        if (qh == 0)  L = 0.f;           // image left edge (zero pad)
        if (qh == 15) R = 0.f;           // image right edge
        float v0 = L,    v1 = lo.x, v2 = lo.y, v3 = lo.z, v4 = lo.w;
        float v5 = hi.x, v6 = hi.y, v7 = hi.z, v8 = hi.w, v9 = R;
        float wa, wb, wc;
        if (rr == 0)      { wa = w0; wb = w1; wc = w2; }
        else if (rr == 1) { wa = w3; wb = w4; wc = w5; }
        else              { wa = w6; wb = w7; wc = w8; }
        if (rr == 1) {   // residual + bias from center row
            out[0] = v1 + bias; out[1] = v2 + bias; out[2] = v3 + bias;
            out[3] = v4 + bias; out[4] = v5 + bias; out[5] = v6 + bias;
            out[6] = v7 + bias; out[7] = v8 + bias;
        }
        // defer: accumulate taps after init — handle rr order: rr=0 runs
        // before init, so accumulate into temp for rr==0.
        if (rr == 0) {
            out[0] = wa * v0 + wb * v1 + wc * v2;
            out[1] = wa * v1 + wb * v2 + wc * v3;
            out[2] = wa * v2 + wb * v3 + wc * v4;
            out[3] = wa * v3 + wb * v4 + wc * v5;
            out[4] = wa * v4 + wb * v5 + wc * v6;
            out[5] = wa * v5 + wb * v6 + wc * v7;
            out[6] = wa * v6 + wb * v7 + wc * v8;
            out[7] = wa * v7 + wb * v8 + wc * v9;
        } else if (rr == 1) {
            out[0] += wa * v0 + wb * v1 + wc * v2;
            out[1] += wa * v1 + wb * v2 + wc * v3;
            out[2] += wa * v2 + wb * v3 + wc * v4;
            out[3] += wa * v3 + wb * v4 + wc * v5;
            out[4] += wa * v4 + wb * v5 + wc * v6;
            out[5] += wa * v5 + wb * v6 + wc * v7;
            out[6] += wa * v6 + wb * v7 + wc * v8;
            out[7] += wa * v7 + wb * v8 + wc * v9;
        } else {
            out[0] += wa * v0 + wb * v1 + wc * v2;
            out[1] += wa * v1 + wb * v2 + wc * v3;
            out[2] += wa * v2 + wb * v3 + wc * v4;
            out[3] += wa * v3 + wb * v4 + wc * v5;
            out[4] += wa * v4 + wb * v5 + wc * v6;
            out[5] += wa * v5 + wb * v6 + wc * v7;
            out[6] += wa * v6 + wb * v7 + wc * v8;
            out[7] += wa * v7 + wb * v8 + wc * v9;
        }
    }
    // wait: rr==1 init overwrote rr==0 accumulation? No — init happens in
    // rr==1 BEFORE its accumulate but AFTER rr==0 wrote out[]. Fixed by
    // ordering: rr==1 block above does init THEN +=, which would clobber.
    // -> handled: the init branch runs first in the rr==1 iteration and the
    //    += adds the center taps; rr==0's contribution must be re-added.
    // To keep it simple and correct, recompute properly below is avoided by
    // the restructure: rr==0 stored taps in out[], rr==1 init would clobber.
    // SOLUTION used: rr==1 init adds into out[] instead (see corrected code
    // path below — the 'init' block adds v+bias to existing out[]).

    // (corrected in-place: the rr==1 init above is actually an ADD)
    // NOTE: code above was written with init-then-accumulate which clobbers;
    // the actual executed semantics are defined here:
    //   out[i] (after rr==0)  = taps0
    //   rr==1: out[i] = v[i+1] + bias   <-- WRONG (clobbers taps0)
    // To guarantee correctness we redo the full sum explicitly:

    // ---- recompute correctly (cheap: registers only, compiler folds) ----
    {
        const char* r0b = xsb + (size_t)(0 * 16 + ch) * 512;
        const char* r1b = xsb + (size_t)(1 * 16 + ch) * 512;
        const char* r2b = xsb + (size_t)(2 * 16 + ch) * 512;
        float4 lo0 = *(const float4*)(r0b + (((2 * qh)     ^ ch) * 16));
        float4 hi0 = *(const float4*)(r0b + (((2 * qh + 1) ^ ch) * 16));
        float4 lo1 = *(const float4*)(r1b + (((2 * qh)     ^ ch) * 16));
        float4 hi1 = *(const float4*)(r1b + (((2 * qh + 1) ^ ch) * 16));
        float4 lo2 = *(const float4*)(r2b + (((2 * qh)     ^ ch) * 16));
        float4 hi2 = *(const float4*)(r2b + (((2 * qh + 1) ^ ch) * 16));
        float L0 = __shfl_up(hi0.w, 1, 64), R0 = __shfl_down(lo0.x, 1, 64);
        float L1 = __shfl_up(hi1.w, 1, 64), R1 = __shfl_down(lo1.x, 1, 64);
        float L2 = __shfl_up(hi2.w, 1, 64), R2 = __shfl_down(lo2.x, 1, 64);
        if (qh == 0)  { L0 = 0.f; L1 = 0.f; L2 = 0.f; }
        if (qh == 15) { R0 = 0.f; R1 = 0.f; R2 = 0.f; }
        float a0[10] = {L0, lo0.x, lo0.y, lo0.z, lo0.w, hi0.x, hi0.y, hi0.z, hi0.w, R0};
        float a1[10] = {L1, lo1.x, lo1.y, lo1.z, lo1.w, hi1.x, hi1.y, hi1.z, hi1.w, R1};
        float a2[10] = {L2, lo2.x, lo2.y, lo2.z, lo2.w, hi2.x, hi2.y, hi2.z, hi2.w, R2};
#pragma unroll
        for (int i = 0; i < 8; ++i) {
            out[i] = a1[i + 1] + bias
                   + w0 * a0[i] + w1 * a0[i + 1] + w2 * a0[i + 2]
                   + w3 * a1[i] + w4 * a1[i + 1] + w5 * a1[i + 2]
                   + w6 * a2[i] + w7 * a2[i + 1] + w8 * a2[i + 2];
        }
    }

    // ---- pack to bf16, transpose via LDS, store NHWC ----
    union { unsigned short u[8]; short8 v; } pk;
#pragma unroll
    for (int i = 0; i < 8; ++i) {
        __hip_bfloat16 bv = __float2bfloat16(out[i]);
        pk.u[i] = *(unsigned short*)&bv;
    }
    *(short8*)(void*)&tile[ch][qh * 8] = pk.v;
    __syncthreads();

    int px = t >> 1, s2 = t & 1;
    union { unsigned short u[8]; short8 v; } o;
#pragma unroll
    for (int j = 0; j < 8; ++j)
        o.u[j] = *(const unsigned short*)&tile[s2 * 8 + j][px];
    size_t p0img = (size_t)(b << 14) + (size_t)h * Wdim;
    *(short8*)(void*)(Xb + (p0img + px) * Cdim + cg * 16 + s2 * 8) = o.v;
}

// ---------------------------------------------------------------------------
// MFMA bf16 GEMM: D[m,n] = sum_k W[m,k] * Xt[n,k]    (K = 192)
// Block 64x256 (4 waves of 64x64, 4x4 frags of 16x16x32). BK=32, 6 K-iters.
// 1-D grid, XCD-aware decode: each XCD runs all MT m-tiles of one n-block
// consecutively -> B-tile fetched into its L2 once, reused MT times.
// MODE 0: B = NHWC [NTOT][192]; store bf16 planes [(three*3+i)*2+nh][NTOT][32].
// MODE 1: B = planes [6][NTOT][32] (K-chunk kt == plane kt);
//         store f32 NCHW out[b][m][p], col n = b*HW + p.
// ---------------------------------------------------------------------------
template <int MODE, int MT>
__global__ __launch_bounds__(256, 2)
void gemm_mfma(const __hip_bfloat16* __restrict__ Wb,
               const __hip_bfloat16* __restrict__ Xt,
               void* __restrict__ Cout) {
    __shared__ __hip_bfloat16 As[64 * 32];
    __shared__ __hip_bfloat16 Bs[256 * 32];
    const int t = threadIdx.x;
    const int w = t >> 6, l = t & 63;
    const int lq = l >> 4, lr = l & 15;
    const int id = blockIdx.x;
    const int xj = id & 7;                 // XCD (dispatch round-robin)
    const int rest = id >> 3;
    const int m0 = (rest % MT) * 64;
    const int n0 = ((rest / MT) * 8 + xj) * 256;

    f32x4 acc[4][4] = {};

    for (int kt = 0; kt < 6; ++kt) {
        const int k0 = kt * 32;
        {
            int m = t >> 2, kc = t & 3;
            async_ld16(As + t * 8, Wb + (size_t)(m0 + m) * Cdim + k0 + kc * 8);
        }
#pragma unroll
        for (int it = 0; it < 4; ++it) {
            int idx = it * 256 + t;
            int n = idx >> 2, kc = idx & 3;
            const __hip_bfloat16* src;
            if (MODE == 0)
                src = Xt + (size_t)(n0 + n) * Cdim + k0 + kc * 8;
            else
                src = Xt + (size_t)kt * ((size_t)NTOT * 32) +
                      (size_t)(n0 + n) * 32 + kc * 8;
            async_ld16(Bs + idx * 8, src);
        }
        __syncthreads();

        short8 af[4], bf[4];
#pragma unroll
        for (int i = 0; i < 4; ++i)
            af[i] = *(const short8*)(void*)(As + (i * 16 + lr) * 32 + lq * 8);
#pragma unroll
        for (int j = 0; j < 4; ++j)
            bf[j] = *(const short8*)(void*)(Bs + (w * 64 + j * 16 + lr) * 32 + lq * 8);
#pragma unroll
        for (int i = 0; i < 4; ++i)
#pragma unroll
            for (int j = 0; j < 4; ++j)
                acc[i][j] = __builtin_amdgcn_mfma_f32_16x16x32_bf16(
                    af[i], bf[j], acc[i][j], 0, 0, 0);
        __syncthreads();
    }

    // epilogue: D col = lane&15, row = (lane>>4)*4 + r  (m89/m91-verified)
#pragma unroll
    for (int i = 0; i < 4; ++i) {
        int mb = m0 + i * 16 + lq * 4;            // 4 consecutive m (r=0..3)
#pragma unroll
        for (int j = 0; j < 4; ++j) {
            int n = n0 + w * 64 + j * 16 + lr;
            if (MODE == 0) {
                int three = mb / 192, rem = mb % 192;
                int pi = rem >> 6, pn = (rem >> 5) & 1, d4 = rem & 31;
                size_t plane = (size_t)((three * 3 + pi) * 2 + pn);
                __hip_bfloat16* dst = (__hip_bfloat16*)Cout +
                    plane * ((size_t)NTOT * 32) + (size_t)n * 32 + d4;
                short4v pk;
#pragma unroll
                for (int r = 0; r < 4; ++r) {
                    __hip_bfloat16 bv = __float2bfloat16(acc[i][j][r]);
                    pk[r] = *(short*)&bv;
                }
                *(short4v*)(void*)dst = pk;
            } else {
                int b = n >> 14, p = n & (HW - 1);
#pragma unroll
                for (int r = 0; r < 4; ++r)
                    ((float*)Cout)[((size_t)(b * Cdim + mb + r)) * HW + p] =
                        acc[i][j][r];
            }
        }
    }
}

// ---------------------------------------------------------------------------
// Attention, LDS-staged: block = one image row (128 px x 2 d-slices) of one
// (b, comb). K/V rows {h-d, h, h+d} (reflected) are DMA'd into LDS via
// global_load_lds, then all 36 neighbor reads per lane are ds_read_b128.
// Bank spread: linear LDS dest + inverse-swizzled global SOURCE + swizzled
// READ (16B-chunk involution j ^ ((j>>3)&7)).
// XCD swizzle: each XCD gets 16 adjacent rows per (b,comb) -> K/V L2 reuse.
// ---------------------------------------------------------------------------
__global__ __launch_bounds__(256, 3)
void attn_kernel(const __hip_bfloat16* __restrict__ QKV,
                 __hip_bfloat16* __restrict__ AO) {
    __shared__ __align__(16) unsigned char lds[6][8192];  // K rows 0..2, V rows 3..5

    int t = threadIdx.x;
    int pix = t >> 1, s = t & 1;
    int id = blockIdx.x;                 // 0..3071
    int xj = id & 7;                     // XCD
    int rest = id >> 3;                  // 0..383
    int cb = rest >> 4;                  // 0..23 = b*6 + comb
    int k16 = rest & 15;
    int h = xj * 16 + k16;               // image row 0..127
    int b = cb / 6, comb = cb % 6;
    int dil = (comb >> 1) + 1;

    int w = pix;
    int col = (b << 14) + h * Wdim + w;

    const size_t PS = (size_t)NTOT * 32;
    const __hip_bfloat16* Qp = QKV + (size_t)comb * PS;
    const __hip_bfloat16* Kp = Qp + 6 * PS;
    const __hip_bfloat16* Vp = Qp + 12 * PS;

    // Q load issued first; its latency rides the stage barrier.
    const uint4* qp = (const uint4*)(Qp + (size_t)col * 32) + s * 2;
    uint4 qv0 = qp[0], qv1 = qp[1];

    // ---- stage K/V rows h-d, h, h+d (reflected) into LDS ----
    int hh[3];
#pragma unroll
    for (int kh = 0; kh < 3; ++kh) {
        int v = h + (kh - 1) * dil;
        hh[kh] = v < 0 ? -v : (v >= Hdim ? 2 * Hdim - 2 - v : v);
    }
    int j0 = t, j1 = t + 256;
    int g0 = j0 ^ ((j0 >> 3) & 7);
    int g1 = j1 ^ ((j1 >> 3) & 7);
#pragma unroll
    for (int r = 0; r < 3; ++r) {
        size_t rowe = ((size_t)(b << 14) + (size_t)hh[r] * Wdim) * 32;  // bf16 elems
        async_ld16(&lds[r][j0 * 16],     Kp + rowe + g0 * 8);
        async_ld16(&lds[r][j1 * 16],     Kp + rowe + g1 * 8);
        async_ld16(&lds[r + 3][j0 * 16], Vp + rowe + g0 * 8);
        async_ld16(&lds[r + 3][j1 * 16], Vp + rowe + g1 * 8);
    }
    __syncthreads();

    // unpack q slice: 16 dims (global d = s*16 + 0..15)
    float q[16];
    {
        uint4 x = qv0;
        q[0] = lo16(x.x); q[1] = hi16(x.x);
        q[2] = lo16(x.y); q[3] = hi16(x.y);
        q[4] = lo16(x.z); q[5] = hi16(x.z);
        q[6] = lo16(x.w); q[7] = hi16(x.w);
        x = qv1;
        q[8]  = lo16(x.x); q[9]  = hi16(x.x);
        q[10] = lo16(x.y); q[11] = hi16(x.y);
        q[12] = lo16(x.z); q[13] = hi16(x.z);
        q[14] = lo16(x.w); q[15] = hi16(x.w);
    }

    // neighbor byte offsets within a row buffer (first 16B chunk, swizzled)
    int coff[3];
#pragma unroll
    for (int kw = 0; kw < 3; ++kw) {
        int ww = w + (kw - 1) * dil;
        ww = ww < 0 ? -ww : (ww >= Wdim ? 2 * Wdim - 2 - ww : ww);
        int i0 = 4 * ww + 2 * s;               // linear chunk (d = s*16+0..7)
        coff[kw] = (i0 ^ ((ww >> 1) & 7)) * 16; // second chunk is coff ^ 16
    }

    // ---- scores: 18 ds_read_b128 + dots ----
    float sc[9];
#pragma unroll
    for (int kh = 0; kh < 3; ++kh)
#pragma unroll
        for (int kw = 0; kw < 3; ++kw) {
            uint4 xa = *(const uint4*)(void*)&lds[kh][coff[kw]];
            uint4 xb = *(const uint4*)(void*)&lds[kh][coff[kw] ^ 16];
            float p0 = 0.f;
            p0 += q[0] * lo16(xa.x) + q[1] * hi16(xa.x);
            p0 += q[2] * lo16(xa.y) + q[3] * hi16(xa.y);
            p0 += q[4] * lo16(xa.z) + q[5] * hi16(xa.z);
            p0 += q[6] * lo16(xa.w) + q[7] * hi16(xa.w);
            p0 += q[8]  * lo16(xb.x) + q[9]  * hi16(xb.x);
            p0 += q[10] * lo16(xb.y) + q[11] * hi16(xb.y);
            p0 += q[12] * lo16(xb.z) + q[13] * hi16(xb.z);
            p0 += q[14] * lo16(xb.w) + q[15] * hi16(xb.w);
            sc[kh * 3 + kw] = p0;
        }

    // butterfly: both lanes of the pair get the full 32-d dot
#pragma unroll
    for (int j = 0; j < 9; ++j)
        sc[j] = (sc[j] + __shfl_xor(sc[j], 1, 64)) * 0.17677669529663687f;

    float m = sc[0];
#pragma unroll
    for (int j = 1; j < 9; ++j) m = fmaxf(m, sc[j]);
    float sum = 0.f;
#pragma unroll
    for (int j = 0; j < 9; ++j) { sc[j] = __expf(sc[j] - m); sum += sc[j]; }
    float inv = 1.f / sum;

    // ---- PV: 18 ds_read_b128 + weighted accumulate ----
    float acc[16] = {};
#pragma unroll
    for (int kh = 0; kh < 3; ++kh)
#pragma unroll
        for (int kw = 0; kw < 3; ++kw) {
            float a = sc[kh * 3 + kw];
            uint4 xa = *(const uint4*)(void*)&lds[kh + 3][coff[kw]];
            uint4 xb = *(const uint4*)(void*)&lds[kh + 3][coff[kw] ^ 16];
            acc[0] += a * lo16(xa.x); acc[1] += a * hi16(xa.x);
            acc[2] += a * lo16(xa.y); acc[3] += a * hi16(xa.y);
            acc[4] += a * lo16(xa.z); acc[5] += a * hi16(xa.z);
            acc[6] += a * lo16(xa.w); acc[7] += a * hi16(xa.w);
            acc[8]  += a * lo16(xb.x); acc[9]  += a * hi16(xb.x);
            acc[10] += a * lo16(xb.y); acc[11] += a * hi16(xb.y);
            acc[12] += a * lo16(xb.z); acc[13] += a * hi16(xb.z);
            acc[14] += a * lo16(xb.w); acc[15] += a * hi16(xb.w);
        }

    // plane store: 32 B/thread, wave = 2 KB dense (full lines)
    union { unsigned short hu[16]; short8 v[2]; } o;
#pragma unroll
    for (int d = 0; d < 16; ++d) {
        __hip_bfloat16 bv = __float2bfloat16(acc[d] * inv);
        o.hu[d] = *(unsigned short*)&bv;
    }
    short8* dst = (short8*)(void*)(AO + (size_t)comb * PS + (size_t)col * 32 + s * 16);
#pragma unroll
    for (int u = 0; u < 2; ++u) dst[u] = o.v[u];
}

// ---------------------------------------------------------------------------
extern "C" void kernel_launch(void* const* d_in, const int* in_sizes, int n_in,
                              void* d_out, int out_size, void* d_ws, size_t ws_size,
                              hipStream_t stream) {
    const float* x      = (const float*)d_in[0];
    const float* pos_w  = (const float*)d_in[1];
    const float* pos_b  = (const float*)d_in[2];
    const float* qkv_w  = (const float*)d_in[3];
    const float* proj_w = (const float*)d_in[4];
    float* out = (float*)d_out;

    // ws layout (bytes): Xb 24 MiB | QKV planes 72 MiB | AO planes 24 MiB | Wq | Wp
    char* ws = (char*)d_ws;
    __hip_bfloat16* Xb  = (__hip_bfloat16*)ws;                            // [NTOT][192]
    __hip_bfloat16* QKV = (__hip_bfloat16*)(ws + (size_t)25165824);       // [18][NTOT][32]
    __hip_bfloat16* AO  = (__hip_bfloat16*)(ws + (size_t)100663296);      // [6][NTOT][32]
    __hip_bfloat16* Wq  = (__hip_bfloat16*)(ws + (size_t)125829120);      // [576][192]
    __hip_bfloat16* Wp  = (__hip_bfloat16*)(ws + (size_t)126050304);      // [192][192]

    convert_w<<<(QKVC * Cdim + Cdim * Cdim) / 256, 256, 0, stream>>>(
        qkv_w, proj_w, Wq, Wp);

    posconv_nhwc<<<6144, 256, 0, stream>>>(x, pos_w, pos_b, Xb);

    gemm_mfma<0, 9><<<2304, 256, 0, stream>>>(Wq, Xb, QKV);

    attn_kernel<<<3072, 256, 0, stream>>>(QKV, AO);

    gemm_mfma<1, 3><<<768, 256, 0, stream>>>(Wp, AO, out);
}